// Round 5
// baseline (468.335 us; speedup 1.0000x reference)
//
#include <hip/hip_runtime.h>

// H2GCNConv: out[:, 0:128]   = segment_sum(w1 * x[col1], row1)
//            out[:, 128:256] = segment_sum(w2 * x[col2], row2)
// N = 50000, d = 128, out stride = 256 floats.
//
// Round 4b: same as round 4 (4 B scatter records col:16|w_bf16:16, fused
// scatter, int4 hist, vectorized cvt, nontemporal output stores) with the
// nontemporal store expressed via a native ext_vector_type — HIP's float2
// class type is rejected by __builtin_nontemporal_store.

#define N_NODES 50000
#define D 128
#define OUT_STRIDE 256
#define SCAN_B 256

typedef float vf2 __attribute__((ext_vector_type(2)));

static inline size_t align256(size_t x) { return (x + 255) & ~(size_t)255; }

// ---------------- CSR build ----------------

// Histogram rows for both graphs, 4 edges per thread (int4 loads).
__global__ void hist_kernel(const int* __restrict__ ei1, int E1,
                            const int* __restrict__ ei2, int E2,
                            int* cnt1, int* cnt2) {
    int q1 = E1 >> 2;
    int q2 = E2 >> 2;
    int t = blockIdx.x * blockDim.x + threadIdx.x;
    if (t < q1) {
        int4 r = ((const int4*)ei1)[t];
        atomicAdd(&cnt1[r.x], 1); atomicAdd(&cnt1[r.y], 1);
        atomicAdd(&cnt1[r.z], 1); atomicAdd(&cnt1[r.w], 1);
    } else if (t < q1 + q2) {
        int4 r = ((const int4*)ei2)[t - q1];
        atomicAdd(&cnt2[r.x], 1); atomicAdd(&cnt2[r.y], 1);
        atomicAdd(&cnt2[r.z], 1); atomicAdd(&cnt2[r.w], 1);
    } else {
        int u = t - (q1 + q2);
        int t1 = E1 & 3, t2 = E2 & 3;
        if (u < t1) atomicAdd(&cnt1[ei1[(q1 << 2) + u]], 1);
        else if (u - t1 < t2) atomicAdd(&cnt2[ei2[(q2 << 2) + (u - t1)]], 1);
    }
}

// Phase 1: per-block sums. grid = (nb, 2).
__global__ void scan_sums(const int* __restrict__ cnt1, const int* __restrict__ cnt2,
                          int* __restrict__ bsums, int n, int nb) {
    const int* cnt = blockIdx.y ? cnt2 : cnt1;
    int i = blockIdx.x * SCAN_B + threadIdx.x;
    int v = (i < n) ? cnt[i] : 0;
    #pragma unroll
    for (int d = 1; d < 64; d <<= 1) v += __shfl_xor(v, d, 64);
    __shared__ int ws[4];
    if ((threadIdx.x & 63) == 0) ws[threadIdx.x >> 6] = v;
    __syncthreads();
    if (threadIdx.x == 0)
        bsums[blockIdx.y * nb + blockIdx.x] = ws[0] + ws[1] + ws[2] + ws[3];
}

// Phase 2: exclusive scan of block sums in place. grid = 2 blocks. nb <= 256.
__global__ void scan_bsums(int* bsums, int nb) {
    int* b = bsums + blockIdx.x * nb;
    int i = threadIdx.x;
    int v = (i < nb) ? b[i] : 0;
    int lane = threadIdx.x & 63, wid = threadIdx.x >> 6;
    int s = v;
    #pragma unroll
    for (int d = 1; d < 64; d <<= 1) { int t = __shfl_up(s, d, 64); if (lane >= d) s += t; }
    __shared__ int ws[4];
    if (lane == 63) ws[wid] = s;
    __syncthreads();
    int add = 0;
    #pragma unroll
    for (int k = 0; k < 4; ++k) if (k < wid) add += ws[k];
    s += add;
    if (i < nb) b[i] = s - v;   // exclusive
}

// Phase 3: block-local exclusive scan + block base -> off. grid = (nb, 2).
__global__ void scan_apply(const int* __restrict__ cnt1, int* __restrict__ off1,
                           const int* __restrict__ cnt2, int* __restrict__ off2,
                           const int* __restrict__ bsums, int n, int nb) {
    const int* cnt = blockIdx.y ? cnt2 : cnt1;
    int* off       = blockIdx.y ? off2 : off1;
    int base = bsums[blockIdx.y * nb + blockIdx.x];
    int i = blockIdx.x * SCAN_B + threadIdx.x;
    int v = (i < n) ? cnt[i] : 0;
    int lane = threadIdx.x & 63, wid = threadIdx.x >> 6;
    int s = v;
    #pragma unroll
    for (int d = 1; d < 64; d <<= 1) { int t = __shfl_up(s, d, 64); if (lane >= d) s += t; }
    __shared__ int ws[4];
    if (lane == 63) ws[wid] = s;
    __syncthreads();
    int add = 0;
    #pragma unroll
    for (int k = 0; k < 4; ++k) if (k < wid) add += ws[k];
    s += add;
    if (i < n) off[i] = base + s - v;   // exclusive
}

__device__ __forceinline__ unsigned f32_to_bf16_bits(float f) {
    unsigned u = __float_as_uint(f);
    return (u + 0x7fffu + ((u >> 16) & 1u)) >> 16;   // RNE
}

// Fused scatter for both graphs. Record = col (low 16) | bf16(w) (high 16).
// atomicAdd on off[] itself: afterwards off[r] = end of row r.
__global__ void scatter_kernel(const int* __restrict__ ei1,
                               const float* __restrict__ w1, int E1,
                               const int* __restrict__ ei2,
                               const float* __restrict__ w2, int E2,
                               int* off1, unsigned* colw1,
                               int* off2, unsigned* colw2) {
    int t = blockIdx.x * blockDim.x + threadIdx.x;
    const int* ei; const float* w; int* off; unsigned* colw; int e;
    if (t < E1) { ei = ei1; w = w1; off = off1; colw = colw1; e = t; }
    else {
        e = t - E1;
        if (e >= E2) return;
        ei = ei2; w = w2; off = off2; colw = colw2;
    }
    int E = (t < E1) ? E1 : E2;
    int row = ei[e];
    unsigned rec = (unsigned)ei[E + e] | (f32_to_bf16_bits(w[e]) << 16);
    int pos = atomicAdd(&off[row], 1);
    colw[pos] = rec;
}

// x [N,128] f32 -> xb [N,64] packed bf16x2 (RNE). 4 floats / thread.
__global__ void cvt_bf16(const float* __restrict__ x, uint2* __restrict__ xb4, int n4) {
    int i = blockIdx.x * blockDim.x + threadIdx.x;
    if (i >= n4) return;
    float4 v = ((const float4*)x)[i];
    unsigned a = f32_to_bf16_bits(v.x);
    unsigned b = f32_to_bf16_bits(v.y);
    unsigned c = f32_to_bf16_bits(v.z);
    unsigned d = f32_to_bf16_bits(v.w);
    xb4[i] = make_uint2(a | (b << 16), c | (d << 16));
}

// ---------------- SpMM: one wave per (row, graph), bf16 gather ----------------

__device__ __forceinline__ void fma_rec(unsigned p, unsigned rec, float& ax, float& ay) {
    float w = __int_as_float((int)(rec & 0xffff0000u));   // bf16 bits already high
    ax += w * __int_as_float((int)(p << 16));
    ay += w * __int_as_float((int)(p & 0xffff0000u));
}

__global__ void __launch_bounds__(256) spmm_bf16(
        const unsigned* __restrict__ xb,  // [N,64] bf16x2
        const int* __restrict__ off1, const unsigned* __restrict__ colw1,
        const int* __restrict__ off2, const unsigned* __restrict__ colw2,
        float* __restrict__ out) {
    int seg  = (int)((blockIdx.x * blockDim.x + threadIdx.x) >> 6);
    int lane = threadIdx.x & 63;
    if (seg >= 2 * N_NODES) return;
    int g    = (seg >= N_NODES) ? 1 : 0;
    int row  = g ? seg - N_NODES : seg;
    const int*      off  = g ? off2  : off1;
    const unsigned* colw = g ? colw2 : colw1;
    int s = row ? off[row - 1] : 0;
    int e = off[row];

    float ax = 0.f, ay = 0.f;
    int j = s;
    for (; j + 4 <= e; j += 4) {
        unsigned c0 = colw[j];
        unsigned c1 = colw[j + 1];
        unsigned c2 = colw[j + 2];
        unsigned c3 = colw[j + 3];
        unsigned p0 = xb[(size_t)(c0 & 0xffffu) * 64 + lane];
        unsigned p1 = xb[(size_t)(c1 & 0xffffu) * 64 + lane];
        unsigned p2 = xb[(size_t)(c2 & 0xffffu) * 64 + lane];
        unsigned p3 = xb[(size_t)(c3 & 0xffffu) * 64 + lane];
        fma_rec(p0, c0, ax, ay);
        fma_rec(p1, c1, ax, ay);
        fma_rec(p2, c2, ax, ay);
        fma_rec(p3, c3, ax, ay);
    }
    for (; j < e; ++j) {
        unsigned c = colw[j];
        unsigned p = xb[(size_t)(c & 0xffffu) * 64 + lane];
        fma_rec(p, c, ax, ay);
    }
    vf2 r; r.x = ax; r.y = ay;
    vf2* o = (vf2*)(out + (size_t)row * OUT_STRIDE + g * D);
    __builtin_nontemporal_store(r, o + lane);   // stream out; keep xb in L2
}

// ---------------- atomic scatter (fallback if ws too small) ----------------

__global__ void spmm_scatter(const float* __restrict__ x,
                             const int* __restrict__ ei,
                             const float* __restrict__ w,
                             float* __restrict__ out,
                             int E, int col_off) {
    long long gid = (long long)blockIdx.x * blockDim.x + threadIdx.x;
    int e    = (int)(gid >> 5);
    int lane = (int)(gid & 31);
    if (e >= E) return;
    int row  = ei[e];
    int col  = ei[E + e];
    float wv = w[e];
    const float4* xv = (const float4*)(x + (size_t)col * D);
    float4 v = xv[lane];
    float* o = out + (size_t)row * OUT_STRIDE + col_off + lane * 4;
    atomicAdd(o + 0, wv * v.x);
    atomicAdd(o + 1, wv * v.y);
    atomicAdd(o + 2, wv * v.z);
    atomicAdd(o + 3, wv * v.w);
}

extern "C" void kernel_launch(void* const* d_in, const int* in_sizes, int n_in,
                              void* d_out, int out_size, void* d_ws, size_t ws_size,
                              hipStream_t stream) {
    const float* x   = (const float*)d_in[0];
    const int*   ei1 = (const int*)d_in[1];
    const float* w1  = (const float*)d_in[2];
    const int*   ei2 = (const int*)d_in[3];
    const float* w2  = (const float*)d_in[4];
    float* out = (float*)d_out;

    const int E1 = in_sizes[1] / 2;   // 800000
    const int E2 = in_sizes[3] / 2;   // 1600000
    const int block = 256;
    const int nb = (N_NODES + SCAN_B - 1) / SCAN_B;   // 196

    // Workspace: cnt1 | cnt2 | off1 | off2 | bsums | colw1 | colw2 | xb
    size_t cnt_b  = align256((size_t)N_NODES * sizeof(int));
    size_t o_cnt1 = 0;
    size_t o_cnt2 = o_cnt1 + cnt_b;
    size_t o_off1 = o_cnt2 + cnt_b;
    size_t o_off2 = o_off1 + cnt_b;
    size_t o_bsum = o_off2 + cnt_b;
    size_t o_cw1  = o_bsum + align256((size_t)2 * nb * sizeof(int));
    size_t o_cw2  = o_cw1 + align256((size_t)E1 * sizeof(unsigned));
    size_t o_xb   = o_cw2 + align256((size_t)E2 * sizeof(unsigned));
    size_t needed = o_xb + align256((size_t)N_NODES * 64 * sizeof(unsigned));

    if (ws_size < needed) {
        // Fallback: atomic scatter (round-0).
        (void)hipMemsetAsync(d_out, 0, (size_t)out_size * sizeof(float), stream);
        long long th1 = (long long)E1 * 32;
        spmm_scatter<<<(int)((th1 + block - 1) / block), block, 0, stream>>>(
            x, ei1, w1, out, E1, 0);
        long long th2 = (long long)E2 * 32;
        spmm_scatter<<<(int)((th2 + block - 1) / block), block, 0, stream>>>(
            x, ei2, w2, out, E2, D);
        return;
    }

    char* ws = (char*)d_ws;
    int*      cnt1  = (int*)(ws + o_cnt1);
    int*      cnt2  = (int*)(ws + o_cnt2);
    int*      off1  = (int*)(ws + o_off1);
    int*      off2  = (int*)(ws + o_off2);
    int*      bsums = (int*)(ws + o_bsum);
    unsigned* colw1 = (unsigned*)(ws + o_cw1);
    unsigned* colw2 = (unsigned*)(ws + o_cw2);
    unsigned* xb    = (unsigned*)(ws + o_xb);

    // 1. zero counters (cnt1|cnt2 adjacent)
    (void)hipMemsetAsync(cnt1, 0, 2 * cnt_b, stream);

    // 2. histogram rows (4 edges/thread)
    {
        int total = (E1 >> 2) + (E2 >> 2) + (E1 & 3) + (E2 & 3);
        hist_kernel<<<(total + block - 1) / block, block, 0, stream>>>(
            ei1, E1, ei2, E2, cnt1, cnt2);
    }

    // 3. 3-phase exclusive scan (both graphs)
    {
        dim3 g1(nb, 2);
        scan_sums<<<g1, SCAN_B, 0, stream>>>(cnt1, cnt2, bsums, N_NODES, nb);
        scan_bsums<<<2, SCAN_B, 0, stream>>>(bsums, nb);
        scan_apply<<<g1, SCAN_B, 0, stream>>>(cnt1, off1, cnt2, off2, bsums,
                                              N_NODES, nb);
    }

    // 4. pack x to bf16x2 (4 floats/thread)
    {
        int n4 = N_NODES * 32;
        cvt_bf16<<<(n4 + block - 1) / block, block, 0, stream>>>(
            x, (uint2*)xb, n4);
    }

    // 5. fused scatter into 4 B records (mutates off: off[r] -> end of row r)
    {
        int total = E1 + E2;
        scatter_kernel<<<(total + block - 1) / block, block, 0, stream>>>(
            ei1, w1, E1, ei2, w2, E2, off1, colw1, off2, colw2);
    }

    // 6. gather SpMM: one wave per (row, graph)
    {
        long long threads = (long long)2 * N_NODES * 64;
        int grid = (int)((threads + block - 1) / block);
        spmm_bf16<<<grid, block, 0, stream>>>(xb, off1, colw1, off2, colw2, out);
    }
}

// Round 6
// 268.561 us; speedup vs baseline: 1.7439x; 1.7439x over previous
//
#include <hip/hip_runtime.h>

// H2GCNConv: out[:, 0:128]   = segment_sum(w1 * x[col1], row1)
//            out[:, 128:256] = segment_sum(w2 * x[col2], row2)
// N = 50000, d = 128, out stride = 256 floats.
//
// Round 6: two-phase LDS-binned counting sort for the CSR build. Round-5
// counters showed the direct scatter pays exactly one 64 B line writeback per
// 4 B record (153.6 MB for 9.6 MB payload) — random stores never coalesce
// across XCD-private L2s. Now records destined for the same region are staged
// in LDS and flushed as contiguous bursts (~1.4x amp), and the final
// per-bucket counting sort writes fully coalesced + emits off[] directly
// (kills the old 50K-row global hist + 3-phase scan too).

#define N_NODES 50000
#define D 128
#define OUT_STRIDE 256

#define BUCKET_SHIFT 7                     // 128 rows / bucket
#define BROWS (1 << BUCKET_SHIFT)
#define NBUCK ((N_NODES + BROWS - 1) >> BUCKET_SHIFT)   // 391
#define CHUNK 7168                          // edges per bin_scatter WG
#define CAP   5120                          // max records per bucket in LDS

typedef float vf2 __attribute__((ext_vector_type(2)));

static inline size_t align256(size_t x) { return (x + 255) & ~(size_t)255; }

__device__ __forceinline__ unsigned f32_to_bf16_bits(float f) {
    unsigned u = __float_as_uint(f);
    return (u + 0x7fffu + ((u >> 16) & 1u)) >> 16;   // RNE
}

// ---------------- 1. coarse histogram: rows -> 391 buckets x 2 graphs ------

__global__ void __launch_bounds__(256) coarse_hist(
        const int* __restrict__ ei1, int E1,
        const int* __restrict__ ei2, int E2,
        int* __restrict__ bcnt) {           // [2*NBUCK], pre-zeroed
    __shared__ int h[2 * NBUCK];
    for (int i = threadIdx.x; i < 2 * NBUCK; i += 256) h[i] = 0;
    __syncthreads();
    int q1 = E1 >> 2, q2 = E2 >> 2;
    long long total = q1 + q2;
    for (long long i = (long long)blockIdx.x * 256 + threadIdx.x; i < total;
         i += (long long)gridDim.x * 256) {
        if (i < q1) {
            int4 r = ((const int4*)ei1)[i];
            atomicAdd(&h[r.x >> BUCKET_SHIFT], 1);
            atomicAdd(&h[r.y >> BUCKET_SHIFT], 1);
            atomicAdd(&h[r.z >> BUCKET_SHIFT], 1);
            atomicAdd(&h[r.w >> BUCKET_SHIFT], 1);
        } else {
            int4 r = ((const int4*)ei2)[i - q1];
            atomicAdd(&h[NBUCK + (r.x >> BUCKET_SHIFT)], 1);
            atomicAdd(&h[NBUCK + (r.y >> BUCKET_SHIFT)], 1);
            atomicAdd(&h[NBUCK + (r.z >> BUCKET_SHIFT)], 1);
            atomicAdd(&h[NBUCK + (r.w >> BUCKET_SHIFT)], 1);
        }
    }
    if (blockIdx.x == 0) {   // tails if E not divisible by 4
        int t1 = E1 & 3, t2 = E2 & 3;
        int t = threadIdx.x;
        if (t < t1) atomicAdd(&h[ei1[(q1 << 2) + t] >> BUCKET_SHIFT], 1);
        else if (t - t1 < t2)
            atomicAdd(&h[NBUCK + (ei2[(q2 << 2) + (t - t1)] >> BUCKET_SHIFT)], 1);
    }
    __syncthreads();
    for (int i = threadIdx.x; i < 2 * NBUCK; i += 256)
        if (h[i]) atomicAdd(&bcnt[i], h[i]);
}

// ---------------- 2. scan bucket counts -> bases (1 workgroup) -------------

__global__ void __launch_bounds__(256) bucket_scan(
        const int* __restrict__ bcnt, int* __restrict__ bsBase,
        int* __restrict__ bsFill) {
    __shared__ int wsum[4];
    int t = threadIdx.x, lane = t & 63, wid = t >> 6;
    for (int g = 0; g < 2; ++g) {
        const int* c = bcnt + g * NBUCK;
        int i0 = 2 * t, i1 = 2 * t + 1;
        int v0 = (i0 < NBUCK) ? c[i0] : 0;
        int v1 = (i1 < NBUCK) ? c[i1] : 0;
        int p = v0 + v1, s = p;
        #pragma unroll
        for (int d = 1; d < 64; d <<= 1) { int u = __shfl_up(s, d, 64); if (lane >= d) s += u; }
        if (lane == 63) wsum[wid] = s;
        __syncthreads();
        int add = 0;
        #pragma unroll
        for (int k = 0; k < 4; ++k) if (k < wid) add += wsum[k];
        s += add;                      // inclusive over pairs
        int excl = s - p;
        if (i0 < NBUCK) { bsBase[g * NBUCK + i0] = excl;      bsFill[g * NBUCK + i0] = excl; }
        if (i1 < NBUCK) { bsBase[g * NBUCK + i1] = excl + v0; bsFill[g * NBUCK + i1] = excl + v0; }
        __syncthreads();               // wsum reuse
    }
}

// ---------------- 3. binned scatter: edges -> bucket-grouped records -------

__global__ void __launch_bounds__(256) bin_scatter(
        const int* __restrict__ ei1, const float* __restrict__ w1, int E1, int nch1,
        const int* __restrict__ ei2, const float* __restrict__ w2, int E2,
        int* __restrict__ bsFill, uint2* __restrict__ inter) {
    int g, chunk;
    if ((int)blockIdx.x < nch1) { g = 0; chunk = blockIdx.x; }
    else                        { g = 1; chunk = blockIdx.x - nch1; }
    const int*   ei = g ? ei2 : ei1;
    const float* w  = g ? w2  : w1;
    int E           = g ? E2  : E1;
    uint2* out      = inter + (g ? E1 : 0);
    int*   fill     = bsFill + g * NBUCK;
    int e0  = chunk * CHUNK;
    int cnt = min(CHUNK, E - e0);

    __shared__ uint2 stage[CHUNK];              // 56 KB
    __shared__ int cntb[NBUCK], cur[NBUCK], gbase[NBUCK];
    __shared__ int wsum[4];
    int t = threadIdx.x, lane = t & 63, wid = t >> 6;
    for (int b = t; b < NBUCK; b += 256) cntb[b] = 0;
    __syncthreads();
    // pass 1: count bins
    for (int i = t; i < cnt; i += 256)
        atomicAdd(&cntb[ei[e0 + i] >> BUCKET_SHIFT], 1);
    __syncthreads();
    // exclusive scan over 391 bins (2 elems/thread, element-ordered pairs)
    {
        int i0 = 2 * t, i1 = 2 * t + 1;
        int v0 = (i0 < NBUCK) ? cntb[i0] : 0;
        int v1 = (i1 < NBUCK) ? cntb[i1] : 0;
        int p = v0 + v1, s = p;
        #pragma unroll
        for (int d = 1; d < 64; d <<= 1) { int u = __shfl_up(s, d, 64); if (lane >= d) s += u; }
        if (lane == 63) wsum[wid] = s;
        __syncthreads();
        int add = 0;
        #pragma unroll
        for (int k = 0; k < 4; ++k) if (k < wid) add += wsum[k];
        s += add;
        int excl = s - p;
        if (i0 < NBUCK) cur[i0] = excl;
        if (i1 < NBUCK) cur[i1] = excl + v0;
    }
    __syncthreads();
    // reserve global space per bin
    for (int b = t; b < NBUCK; b += 256) {
        int c = cntb[b];
        gbase[b] = c ? atomicAdd(&fill[b], c) : 0;
    }
    __syncthreads();
    // pass 2: rank + stage
    for (int i = t; i < cnt; i += 256) {
        int row = ei[e0 + i];
        int col = ei[E + e0 + i];
        unsigned rec = (unsigned)col | (f32_to_bf16_bits(w[e0 + i]) << 16);
        int b = row >> BUCKET_SHIFT;
        int pos = atomicAdd(&cur[b], 1);
        stage[pos] = make_uint2((unsigned)(row & (BROWS - 1)), rec);
    }
    __syncthreads();
    // flush each bin as a contiguous burst (wave per bin, round-robin)
    for (int b = wid; b < NBUCK; b += 4) {
        int c = cntb[b];
        if (!c) continue;
        int s0 = cur[b] - c;         // cur[b] is now end-of-bin in stage
        int gb = gbase[b];
        for (int i = lane; i < c; i += 64)
            out[gb + i] = stage[s0 + i];
    }
}

// ---------------- 4. per-bucket counting sort -> colw + off ----------------

__global__ void __launch_bounds__(256) bucket_sort(
        const int* __restrict__ bsBase, const int* __restrict__ bsFill,
        const uint2* __restrict__ inter, unsigned* __restrict__ colw,
        int* __restrict__ off1, int* __restrict__ off2, int E1) {
    int b = blockIdx.x, g = blockIdx.y;
    int base = bsBase[g * NBUCK + b];
    int cnt  = bsFill[g * NBUCK + b] - base;
    const uint2* src = inter + (g ? E1 : 0) + base;
    unsigned*    dst = colw  + (g ? E1 : 0) + base;
    int*         off = g ? off2 : off1;

    __shared__ unsigned char rl[CAP];   // 5 KB
    __shared__ unsigned recs[CAP];      // 20 KB
    __shared__ unsigned outb[CAP];      // 20 KB
    __shared__ int crow[BROWS], cur[BROWS];
    __shared__ int wsum[4];
    int t = threadIdx.x, lane = t & 63, wid = t >> 6;
    if (t < BROWS) crow[t] = 0;
    __syncthreads();
    bool fits = (cnt <= CAP);
    // load (if fits) + count rows
    for (int i = t; i < cnt; i += 256) {
        uint2 v = src[i];
        if (fits) { rl[i] = (unsigned char)v.x; recs[i] = v.y; }
        atomicAdd(&crow[v.x], 1);
    }
    __syncthreads();
    // scan 128 row counts; write off ends
    int v = (t < BROWS) ? crow[t] : 0;
    int s = v;
    #pragma unroll
    for (int d = 1; d < 64; d <<= 1) { int u = __shfl_up(s, d, 64); if (lane >= d) s += u; }
    if (lane == 63) wsum[wid] = s;
    __syncthreads();
    int add = 0;
    #pragma unroll
    for (int k = 0; k < 4; ++k) if (k < wid) add += wsum[k];
    s += add;                           // inclusive
    if (t < BROWS) {
        cur[t] = s - v;                 // exclusive start within bucket
        int grow = (b << BUCKET_SHIFT) + t;
        if (grow < N_NODES) off[grow] = base + s;   // end of row's segment
    }
    __syncthreads();
    // scatter by row
    if (fits) {
        for (int i = t; i < cnt; i += 256) {
            int pos = atomicAdd(&cur[rl[i]], 1);
            outb[pos] = recs[i];
        }
        __syncthreads();
        for (int i = t; i < cnt; i += 256) dst[i] = outb[i];   // coalesced
    } else {
        // overflow fallback (never for this data): direct uncoalesced
        for (int i = t; i < cnt; i += 256) {
            uint2 vv = src[i];
            int pos = atomicAdd(&cur[vv.x], 1);
            dst[pos] = vv.y;
        }
    }
}

// ---------------- 5. x -> bf16x2 pack --------------------------------------

__global__ void cvt_bf16(const float* __restrict__ x, uint2* __restrict__ xb4, int n4) {
    int i = blockIdx.x * blockDim.x + threadIdx.x;
    if (i >= n4) return;
    float4 v = ((const float4*)x)[i];
    unsigned a = f32_to_bf16_bits(v.x);
    unsigned b = f32_to_bf16_bits(v.y);
    unsigned c = f32_to_bf16_bits(v.z);
    unsigned d = f32_to_bf16_bits(v.w);
    xb4[i] = make_uint2(a | (b << 16), c | (d << 16));
}

// ---------------- 6. SpMM: one wave per (row, graph), bf16 gather ----------

__device__ __forceinline__ void fma_rec(unsigned p, unsigned rec, float& ax, float& ay) {
    float w = __int_as_float((int)(rec & 0xffff0000u));   // bf16 bits already high
    ax += w * __int_as_float((int)(p << 16));
    ay += w * __int_as_float((int)(p & 0xffff0000u));
}

__global__ void __launch_bounds__(256) spmm_bf16(
        const unsigned* __restrict__ xb,  // [N,64] bf16x2
        const int* __restrict__ off1, const unsigned* __restrict__ colw1,
        const int* __restrict__ off2, const unsigned* __restrict__ colw2,
        float* __restrict__ out) {
    int seg  = (int)((blockIdx.x * blockDim.x + threadIdx.x) >> 6);
    int lane = threadIdx.x & 63;
    if (seg >= 2 * N_NODES) return;
    int g    = (seg >= N_NODES) ? 1 : 0;
    int row  = g ? seg - N_NODES : seg;
    const int*      off  = g ? off2  : off1;
    const unsigned* colw = g ? colw2 : colw1;
    int s = row ? off[row - 1] : 0;
    int e = off[row];

    float ax = 0.f, ay = 0.f;
    int j = s;
    for (; j + 4 <= e; j += 4) {
        unsigned c0 = colw[j];
        unsigned c1 = colw[j + 1];
        unsigned c2 = colw[j + 2];
        unsigned c3 = colw[j + 3];
        unsigned p0 = xb[(size_t)(c0 & 0xffffu) * 64 + lane];
        unsigned p1 = xb[(size_t)(c1 & 0xffffu) * 64 + lane];
        unsigned p2 = xb[(size_t)(c2 & 0xffffu) * 64 + lane];
        unsigned p3 = xb[(size_t)(c3 & 0xffffu) * 64 + lane];
        fma_rec(p0, c0, ax, ay);
        fma_rec(p1, c1, ax, ay);
        fma_rec(p2, c2, ax, ay);
        fma_rec(p3, c3, ax, ay);
    }
    for (; j < e; ++j) {
        unsigned c = colw[j];
        unsigned p = xb[(size_t)(c & 0xffffu) * 64 + lane];
        fma_rec(p, c, ax, ay);
    }
    vf2 r; r.x = ax; r.y = ay;
    vf2* o = (vf2*)(out + (size_t)row * OUT_STRIDE + g * D);
    __builtin_nontemporal_store(r, o + lane);
}

// ---------------- atomic scatter (fallback if ws too small) ----------------

__global__ void spmm_scatter(const float* __restrict__ x,
                             const int* __restrict__ ei,
                             const float* __restrict__ w,
                             float* __restrict__ out,
                             int E, int col_off) {
    long long gid = (long long)blockIdx.x * blockDim.x + threadIdx.x;
    int e    = (int)(gid >> 5);
    int lane = (int)(gid & 31);
    if (e >= E) return;
    int row  = ei[e];
    int col  = ei[E + e];
    float wv = w[e];
    const float4* xv = (const float4*)(x + (size_t)col * D);
    float4 v = xv[lane];
    float* o = out + (size_t)row * OUT_STRIDE + col_off + lane * 4;
    atomicAdd(o + 0, wv * v.x);
    atomicAdd(o + 1, wv * v.y);
    atomicAdd(o + 2, wv * v.z);
    atomicAdd(o + 3, wv * v.w);
}

extern "C" void kernel_launch(void* const* d_in, const int* in_sizes, int n_in,
                              void* d_out, int out_size, void* d_ws, size_t ws_size,
                              hipStream_t stream) {
    const float* x   = (const float*)d_in[0];
    const int*   ei1 = (const int*)d_in[1];
    const float* w1  = (const float*)d_in[2];
    const int*   ei2 = (const int*)d_in[3];
    const float* w2  = (const float*)d_in[4];
    float* out = (float*)d_out;

    const int E1 = in_sizes[1] / 2;   // 800000
    const int E2 = in_sizes[3] / 2;   // 1600000
    const int block = 256;

    // Workspace: bcnt | bsBase | bsFill | off1 | off2 | inter | colw | xb
    size_t buck_b = align256((size_t)2 * NBUCK * sizeof(int));
    size_t off_b  = align256((size_t)N_NODES * sizeof(int));
    size_t o_bcnt = 0;
    size_t o_base = o_bcnt + buck_b;
    size_t o_fill = o_base + buck_b;
    size_t o_off1 = o_fill + buck_b;
    size_t o_off2 = o_off1 + off_b;
    size_t o_int  = o_off2 + off_b;
    size_t o_colw = o_int + align256((size_t)(E1 + E2) * sizeof(uint2));
    size_t o_xb   = o_colw + align256((size_t)(E1 + E2) * sizeof(unsigned));
    size_t needed = o_xb + align256((size_t)N_NODES * 64 * sizeof(unsigned));

    if (ws_size < needed) {
        // Fallback: atomic scatter (round-0).
        (void)hipMemsetAsync(d_out, 0, (size_t)out_size * sizeof(float), stream);
        long long th1 = (long long)E1 * 32;
        spmm_scatter<<<(int)((th1 + block - 1) / block), block, 0, stream>>>(
            x, ei1, w1, out, E1, 0);
        long long th2 = (long long)E2 * 32;
        spmm_scatter<<<(int)((th2 + block - 1) / block), block, 0, stream>>>(
            x, ei2, w2, out, E2, D);
        return;
    }

    char* ws = (char*)d_ws;
    int*      bcnt   = (int*)(ws + o_bcnt);
    int*      bsBase = (int*)(ws + o_base);
    int*      bsFill = (int*)(ws + o_fill);
    int*      off1   = (int*)(ws + o_off1);
    int*      off2   = (int*)(ws + o_off2);
    uint2*    inter  = (uint2*)(ws + o_int);
    unsigned* colw   = (unsigned*)(ws + o_colw);
    unsigned* xb     = (unsigned*)(ws + o_xb);

    // 1. zero bucket counters
    (void)hipMemsetAsync(bcnt, 0, (size_t)2 * NBUCK * sizeof(int), stream);

    // 2. coarse histogram (LDS-aggregated)
    coarse_hist<<<512, block, 0, stream>>>(ei1, E1, ei2, E2, bcnt);

    // 3. bucket bases (1 WG)
    bucket_scan<<<1, block, 0, stream>>>(bcnt, bsBase, bsFill);

    // 4. binned scatter into bucket-grouped intermediate
    {
        int nch1 = (E1 + CHUNK - 1) / CHUNK;
        int nch2 = (E2 + CHUNK - 1) / CHUNK;
        bin_scatter<<<nch1 + nch2, block, 0, stream>>>(
            ei1, w1, E1, nch1, ei2, w2, E2, bsFill, inter);
    }

    // 5. per-bucket counting sort -> final colw + off (coalesced writes)
    {
        dim3 g(NBUCK, 2);
        bucket_sort<<<g, block, 0, stream>>>(bsBase, bsFill, inter, colw,
                                             off1, off2, E1);
    }

    // 6. pack x to bf16x2
    {
        int n4 = N_NODES * 32;
        cvt_bf16<<<(n4 + block - 1) / block, block, 0, stream>>>(
            x, (uint2*)xb, n4);
    }

    // 7. gather SpMM: one wave per (row, graph)
    {
        long long threads = (long long)2 * N_NODES * 64;
        int grid = (int)((threads + block - 1) / block);
        spmm_bf16<<<grid, block, 0, stream>>>(xb, off1, colw, off2, colw + E1, out);
    }
}